// Round 19
// baseline (944.724 us; speedup 1.0000x reference)
//
#include <hip/hip_runtime.h>
#include <hip/hip_bf16.h>

typedef unsigned short u16;
typedef unsigned int u32;
typedef __attribute__((ext_vector_type(8))) short short8;
typedef __attribute__((ext_vector_type(4))) float f32x4;
typedef __attribute__((ext_vector_type(2))) unsigned int u32x2;

#define DEVFN static __device__ __forceinline__

DEVFN u16 f2bf(float f) {
  union { float f; u32 i; } v; v.f = f;
  return (u16)((v.i + 0x7fffu + ((v.i >> 16) & 1u)) >> 16);
}
DEVFN float bf2f(u16 u) {
  union { u32 i; float f; } v; v.i = ((u32)u) << 16; return v.f;
}
DEVFN void gload_lds16(const void* g, void* l) {
  __builtin_amdgcn_global_load_lds((const __attribute__((address_space(1))) u32*)g,
                                   (__attribute__((address_space(3))) u32*)l, 16, 0, 0);
}
DEVFN u32 cvt_pk_bf16(float lo, float hi) {
  u32 r;
  asm("v_cvt_pk_bf16_f32 %0, %1, %2" : "=v"(r) : "v"(lo), "v"(hi));
  return r;
}
// tanh-form GELU via sigmoid: gelu(x) ~= x * sigmoid(1.59577x + 0.0713548x^3)
DEVFN float gelu_fast(float v) {
  float s = v * (1.5957691216057308f + 0.07135481627f * v * v);
  return v / (1.0f + __expf(-s));
}

// ---------------- weight transpose: W (K x N, f32) -> Wt (N x K, bf16) ----------
__global__ void wtrans_kernel(const float* __restrict__ w, u16* __restrict__ wt, int K, int N) {
  int idx = blockIdx.x * 256 + threadIdx.x;
  if (idx >= K * N) return;
  int n = idx / K, k = idx - n * K;
  wt[idx] = f2bf(w[(size_t)k * N + n]);
}

// ------- bias+mask table in MFMA C-fragment layout, PRE-SCALED by 1/ln2 --------
__global__ void biasmask_kernel(const float* __restrict__ rpb, float* __restrict__ bm) {
  int idx = blockIdx.x * 256 + threadIdx.x;
  if (idx >= 4 * 8 * 16 * 64 * 4) return;
  int rg = idx & 3;
  int lane = (idx >> 2) & 63;
  int mrb = (idx >> 8) & 15;
  int h = (idx >> 12) & 7;
  int t = idx >> 15;
  int m = mrb >> 2, rb = mrb & 3;
  int g4 = lane >> 4, l15 = lane & 15;
  int nn = m * 16 + g4 * 4 + rg;     // key index
  int r = rb * 16 + l15;             // query index
  float v;
  if (nn >= 49) v = -1e9f;
  else if (r >= 49) v = 0.f;
  else {
    int i1 = r / 7, j1 = r - i1 * 7, i2 = nn / 7, j2 = nn - i2 * 7;
    int rel = (i1 - i2 + 6) * 13 + (j1 - j2 + 6);
    v = rpb[rel * 8 + h];
    int ry1 = (t & 2) ? (i1 < 4 ? 1 : 2) : 0;
    int rx1 = (t & 1) ? (j1 < 4 ? 1 : 2) : 0;
    int ry2 = (t & 2) ? (i2 < 4 ? 1 : 2) : 0;
    int rx2 = (t & 1) ? (j2 < 4 ? 1 : 2) : 0;
    if (ry1 * 3 + rx1 != ry2 * 3 + rx2) v += -100.0f;
  }
  bm[idx] = v * 1.4426950408889634f;   // log2 domain
}

// ---------------- LayerNorm1 (one wave per token) with shift+window gather -----
__global__ void ln_kernel(const float* __restrict__ x, const float* __restrict__ gg,
                          const float* __restrict__ bb, u16* __restrict__ out) {
  int gw = (int)(((u32)blockIdx.x * blockDim.x + threadIdx.x) >> 6);
  int lane = threadIdx.x & 63;
  u32 tw = (u32)gw;
  u32 b_ = tw / 49u, nn = tw - b_ * 49u;
  u32 bbi = b_ >> 6, wv = b_ & 63u, wy = wv >> 3, wx = wv & 7u;
  u32 ii = nn / 7u, jj = nn - ii * 7u;
  u32 y = wy * 7u + ii + 3u;  if (y >= 56u) y -= 56u;
  u32 xx = wx * 7u + jj + 3u; if (xx >= 56u) xx -= 56u;
  size_t src = ((size_t)(bbi * 3136u + y * 56u + xx)) * 256u;
  float4 v = *(const float4*)(x + src + lane * 4);
  float s = v.x + v.y + v.z + v.w;
  float s2 = v.x * v.x + v.y * v.y + v.z * v.z + v.w * v.w;
  #pragma unroll
  for (int m = 1; m < 64; m <<= 1) {
    s += __shfl_xor(s, m, 64);
    s2 += __shfl_xor(s2, m, 64);
  }
  float mu = s * (1.f / 256.f);
  float var = s2 * (1.f / 256.f) - mu * mu;
  float rs = rsqrtf(var + 1e-5f);
  float4 g4 = *(const float4*)(gg + lane * 4);
  float4 b4 = *(const float4*)(bb + lane * 4);
  ushort4 o;
  o.x = f2bf((v.x - mu) * rs * g4.x + b4.x);
  o.y = f2bf((v.y - mu) * rs * g4.y + b4.y);
  o.z = f2bf((v.z - mu) * rs * g4.z + b4.z);
  o.w = f2bf((v.w - mu) * rs * g4.w + b4.w);
  *(ushort4*)(out + (size_t)gw * 256u + lane * 4) = o;
}

// ---------------- QKV GEMM: 128x128 tile, 256 threads (4 waves 2x2) ------------
// Q pre-scaled by d^-0.5 / ln2 (softmax runs in exp2 domain)
__global__ __launch_bounds__(256, 2) void qkv_gemm(
    const u16* __restrict__ A, const u16* __restrict__ Bt,
    const float* __restrict__ bias, u16* __restrict__ C) {
  __shared__ __align__(16) u16 Ab[128 * 64];
  __shared__ __align__(16) u16 Bb[128 * 64];
  const int t = threadIdx.x;
  const int w = t >> 6, lane = t & 63;
  const int wm = w >> 1, wn = w & 1;
  const int g4 = lane >> 4, l15 = lane & 15;
  int bid = blockIdx.x;
  int chunk = (int)gridDim.x >> 3;
  int logical = (bid & 7) * chunk + (bid >> 3);
  const int bx = logical % 6, by = logical / 6;
  const int rowBase = by * 128;
  const int colBase = bx * 128;
  f32x4 acc[4][4] = {};

  for (int kk = 0; kk < 256; kk += 64) {
    __syncthreads();
    #pragma unroll
    for (int i = 0; i < 4; ++i) {
      int c = i * 256 + t;
      int row = c >> 3, cc = c & 7, scc = cc ^ (row & 7);
      gload_lds16(A + (size_t)(rowBase + row) * 256 + kk + scc * 8,
                  &Ab[(i * 256 + w * 64) * 8]);
    }
    #pragma unroll
    for (int i = 0; i < 4; ++i) {
      int c = i * 256 + t;
      int row = c >> 3, cc = c & 7, scc = cc ^ (row & 7);
      gload_lds16(Bt + (size_t)(colBase + row) * 256 + kk + scc * 8,
                  &Bb[(i * 256 + w * 64) * 8]);
    }
    __syncthreads();
    #pragma unroll
    for (int ks = 0; ks < 2; ++ks) {
      short8 af[4], bf[4];
      const int kb = (ks * 32 + g4 * 8) * 2;
      #pragma unroll
      for (int m = 0; m < 4; ++m) {
        int row = wm * 64 + m * 16 + l15;
        af[m] = *(const short8*)((const char*)Ab + row * 128 + (kb ^ ((row & 7) << 4)));
      }
      #pragma unroll
      for (int n = 0; n < 4; ++n) {
        int row = wn * 64 + n * 16 + l15;
        bf[n] = *(const short8*)((const char*)Bb + row * 128 + (kb ^ ((row & 7) << 4)));
      }
      #pragma unroll
      for (int m = 0; m < 4; ++m)
        #pragma unroll
        for (int n = 0; n < 4; ++n)
          acc[m][n] = __builtin_amdgcn_mfma_f32_16x16x32_bf16(af[m], bf[n], acc[m][n], 0, 0, 0);
    }
  }
  // Q scale = 0.17677669529663687 * 1.4426950408889634 (exp2 domain)
  const float scale = (colBase < 256) ? 0.2550348842333775f : 1.0f;
  float bv[4];
  #pragma unroll
  for (int n = 0; n < 4; ++n) bv[n] = bias[colBase + wn * 64 + n * 16 + l15];
  #pragma unroll
  for (int m = 0; m < 4; ++m)
    #pragma unroll
    for (int r = 0; r < 4; ++r) {
      int grow = rowBase + wm * 64 + m * 16 + g4 * 4 + r;
      #pragma unroll
      for (int n = 0; n < 4; ++n) {
        int gcol = colBase + wn * 64 + n * 16 + l15;
        C[(size_t)grow * 768 + gcol] = f2bf((acc[m][n][r] + bv[n]) * scale);
      }
    }
}

// ---------------- mega attention: attn + proj + residual + LN2 per window ------
// proj B-fragments read directly from L2-resident wtp (no staging, 4 barriers total)
__global__ __launch_bounds__(512, 4) void attn_mega(
    const u16* __restrict__ qkv, const float* __restrict__ bm2,
    const u16* __restrict__ wtp, const float* __restrict__ pbias,
    const float* __restrict__ x, const float* __restrict__ g2,
    const float* __restrict__ b2, u16* __restrict__ x2g,
    u16* __restrict__ lno) {
  __shared__ __align__(16) char smem[65536];
  __shared__ __align__(16) float redbuf[64][4][2];
  const int t = threadIdx.x;
  const int w = t >> 6, lane = t & 63;
  const int g4 = lane >> 4, l15 = lane & 15;
  const int b_ = blockIdx.x;
  const int wv = b_ & 63, wy = wv >> 3, wx = wv & 7;
  const int mtype = ((wy == 7) ? 2 : 0) + ((wx == 7) ? 1 : 0);
  const int h = w;
  const size_t gbase = (size_t)b_ * 49u * 768u;

  short8 qf[4], kf[4];
  #pragma unroll
  for (int i = 0; i < 4; ++i) {
    int r = i * 16 + l15; if (r > 48) r = 48;
    qf[i] = *(const short8*)(qkv + gbase + (size_t)r * 768 + h * 32 + g4 * 8);
    kf[i] = *(const short8*)(qkv + gbase + (size_t)r * 768 + 256 + h * 32 + g4 * 8);
  }
  f32x4 s[4][4];
  const float* bmp = bm2 + ((size_t)(mtype * 8 + h) * 16) * 256 + lane * 4;
  #pragma unroll
  for (int m = 0; m < 4; ++m)
    #pragma unroll
    for (int rb = 0; rb < 4; ++rb)
      s[m][rb] = *(const f32x4*)(bmp + (m * 4 + rb) * 256);
  #pragma unroll
  for (int m = 0; m < 4; ++m)
    #pragma unroll
    for (int rb = 0; rb < 4; ++rb)
      s[m][rb] = __builtin_amdgcn_mfma_f32_16x16x32_bf16(kf[m], qf[rb], s[m][rb], 0, 0, 0);

  short8 vf[2][2];
  #pragma unroll
  for (int ks = 0; ks < 2; ++ks) {
    #pragma unroll
    for (int nd = 0; nd < 2; ++nd) {
      int dd = nd * 16 + l15;
      #pragma unroll
      for (int j = 0; j < 8; ++j) {
        int n = ks * 32 + g4 * 8 + j;
        vf[ks][nd][j] = (short)qkv[gbase + (size_t)n * 768 + 512 + h * 32 + dd];
      }
    }
  }

  char* pw = smem + w * 8192;
  #pragma unroll
  for (int rb = 0; rb < 4; ++rb) {
    int r = rb * 16 + l15;
    float mx = -1e30f;
    #pragma unroll
    for (int m = 0; m < 4; ++m)
      #pragma unroll
      for (int rg = 0; rg < 4; ++rg)
        mx = fmaxf(mx, s[m][rb][rg]);
    mx = fmaxf(mx, __shfl_xor(mx, 16, 64));
    mx = fmaxf(mx, __shfl_xor(mx, 32, 64));
    float sum = 0.f;
    #pragma unroll
    for (int m = 0; m < 4; ++m)
      #pragma unroll
      for (int rg = 0; rg < 4; ++rg) {
        float e = exp2f(s[m][rb][rg] - mx);
        s[m][rb][rg] = e;
        sum += e;
      }
    sum += __shfl_xor(sum, 16, 64);
    sum += __shfl_xor(sum, 32, 64);
    float inv = 1.0f / sum;
    #pragma unroll
    for (int m = 0; m < 4; ++m) {
      u32x2 pk;
      pk.x = cvt_pk_bf16(s[m][rb][0] * inv, s[m][rb][1] * inv);
      pk.y = cvt_pk_bf16(s[m][rb][2] * inv, s[m][rb][3] * inv);
      int nn0 = m * 16 + g4 * 4;
      *(u32x2*)(pw + r * 128 + ((nn0 * 2) ^ ((r & 7) << 4))) = pk;
    }
  }

  f32x4 o[4][2] = {};
  #pragma unroll
  for (int ks = 0; ks < 2; ++ks) {
    short8 pf[4];
    const int kbyt = (ks * 32 + g4 * 8) * 2;
    #pragma unroll
    for (int ma = 0; ma < 4; ++ma) {
      int r = ma * 16 + l15;
      pf[ma] = *(const short8*)(pw + r * 128 + (kbyt ^ ((r & 7) << 4)));
    }
    #pragma unroll
    for (int ma = 0; ma < 4; ++ma)
      #pragma unroll
      for (int nd = 0; nd < 2; ++nd)
        o[ma][nd] = __builtin_amdgcn_mfma_f32_16x16x32_bf16(pf[ma], vf[ks][nd], o[ma][nd], 0, 0, 0);
  }

  const int wm2 = w >> 2, wn2 = w & 3;
  const u32 bbi = (u32)b_ >> 6;
  float xr[2][4][4];
  #pragma unroll
  for (int mf = 0; mf < 2; ++mf)
    #pragma unroll
    for (int rg = 0; rg < 4; ++rg) {
      int r = wm2 * 32 + mf * 16 + g4 * 4 + rg;
      u32 ii = (u32)r / 7u, jj = (u32)r - ii * 7u;
      u32 y = (u32)wy * 7u + ii + 3u;  if (y >= 56u) y -= 56u;
      u32 xx = (u32)wx * 7u + jj + 3u; if (xx >= 56u) xx -= 56u;
      size_t orowx = ((size_t)(bbi * 3136u + y * 56u + xx)) * 256u;
      #pragma unroll
      for (int nf = 0; nf < 4; ++nf)
        xr[mf][nf][rg] = x[orowx + wn2 * 64 + nf * 16 + l15];
    }

  __syncthreads();   // all PV done; P region reused for attnout

  // attnout [64][512B] bf16, XOR-swizzled, at smem[0,32768)
  #pragma unroll
  for (int ma = 0; ma < 4; ++ma)
    #pragma unroll
    for (int nd = 0; nd < 2; ++nd)
      #pragma unroll
      for (int rg = 0; rg < 4; ++rg) {
        int r = ma * 16 + g4 * 4 + rg;
        int colb = (h * 32 + nd * 16 + l15) * 2;
        *(u16*)(smem + r * 512 + (colb ^ ((r & 7) << 4))) = f2bf(o[ma][nd][rg]);
      }
  __syncthreads();

  // proj GEMM 64x256 = attnout(LDS) @ wtp^T(direct from L2) — no staging barriers
  f32x4 ap[2][4] = {};
  #pragma unroll
  for (int kk = 0; kk < 256; kk += 64) {
    #pragma unroll
    for (int ks2 = 0; ks2 < 2; ++ks2) {
      short8 afr[2], bfr[4];
      int k = kk + ks2 * 32 + g4 * 8;
      #pragma unroll
      for (int nf = 0; nf < 4; ++nf) {
        int n = wn2 * 64 + nf * 16 + l15;
        bfr[nf] = *(const short8*)(wtp + (size_t)n * 256 + k);
      }
      #pragma unroll
      for (int mf = 0; mf < 2; ++mf) {
        int r = wm2 * 32 + mf * 16 + l15;
        afr[mf] = *(const short8*)(smem + r * 512 + ((k * 2) ^ ((r & 7) << 4)));
      }
      #pragma unroll
      for (int mf = 0; mf < 2; ++mf)
        #pragma unroll
        for (int nf = 0; nf < 4; ++nf)
          ap[mf][nf] = __builtin_amdgcn_mfma_f32_16x16x32_bf16(afr[mf], bfr[nf], ap[mf][nf], 0, 0, 0);
    }
  }

  float pb4[4];
  #pragma unroll
  for (int nf = 0; nf < 4; ++nf) pb4[nf] = pbias[wn2 * 64 + nf * 16 + l15];
  float vv[2][4][4];
  #pragma unroll
  for (int mf = 0; mf < 2; ++mf)
    #pragma unroll
    for (int rg = 0; rg < 4; ++rg) {
      int r = wm2 * 32 + mf * 16 + g4 * 4 + rg;
      float s1 = 0.f, s2 = 0.f;
      #pragma unroll
      for (int nf = 0; nf < 4; ++nf) {
        float v = ap[mf][nf][rg] + pb4[nf] + xr[mf][nf][rg];
        vv[mf][nf][rg] = v;
        s1 += v; s2 += v * v;
      }
      #pragma unroll
      for (int m2 = 1; m2 < 16; m2 <<= 1) {
        s1 += __shfl_xor(s1, m2, 64);
        s2 += __shfl_xor(s2, m2, 64);
      }
      if (l15 == 0) { redbuf[r][wn2][0] = s1; redbuf[r][wn2][1] = s2; }
    }
  __syncthreads();
  #pragma unroll
  for (int mf = 0; mf < 2; ++mf)
    #pragma unroll
    for (int rg = 0; rg < 4; ++rg) {
      int r = wm2 * 32 + mf * 16 + g4 * 4 + rg;
      if (r < 49) {
        float s1 = redbuf[r][0][0] + redbuf[r][1][0] + redbuf[r][2][0] + redbuf[r][3][0];
        float s2 = redbuf[r][0][1] + redbuf[r][1][1] + redbuf[r][2][1] + redbuf[r][3][1];
        float mu = s1 * (1.f / 256.f);
        float var = s2 * (1.f / 256.f) - mu * mu;
        float rs = rsqrtf(var + 1e-5f);
        size_t orow = ((size_t)b_ * 49u + r) * 256u;
        #pragma unroll
        for (int nf = 0; nf < 4; ++nf) {
          int col = wn2 * 64 + nf * 16 + l15;
          float v = vv[mf][nf][rg];
          x2g[orow + col] = f2bf(v);
          lno[orow + col] = f2bf((v - mu) * rs * g2[col] + b2[col]);
        }
      }
    }
}

// ---------------- MLP GEMMs: 128x128 tile, 256 threads (4 waves 2x2) -----------
// EPI 0: fc1 -> bias + fast gelu -> bf16 hid (row stride 1024)
// EPI 1: fc2 -> bias + x2 residual + un-permute -> fp32 out
template<int EPI>
__global__ __launch_bounds__(256, 2) void mlp_gemm(
    const u16* __restrict__ A, const u16* __restrict__ Bt, int K, int nbx,
    const float* __restrict__ bias, const u16* __restrict__ x2g,
    u16* __restrict__ ho, float* __restrict__ out) {
  __shared__ __align__(16) u16 Ab[128 * 64];
  __shared__ __align__(16) u16 Bb[128 * 64];
  const int t = threadIdx.x;
  const int w = t >> 6, lane = t & 63;
  const int wm = w >> 1, wn = w & 1;
  const int g4 = lane >> 4, l15 = lane & 15;
  int bid = blockIdx.x;
  int chunk = (int)gridDim.x >> 3;
  int logical = (bid & 7) * chunk + (bid >> 3);
  const int bx = logical % nbx, by = logical / nbx;
  const int rowBase = by * 128;
  const int colBase = bx * 128;
  f32x4 acc[4][4] = {};

  for (int kk = 0; kk < K; kk += 64) {
    __syncthreads();
    #pragma unroll
    for (int i = 0; i < 4; ++i) {
      int c = i * 256 + t;
      int row = c >> 3, cc = c & 7, scc = cc ^ (row & 7);
      gload_lds16(A + (size_t)(rowBase + row) * K + kk + scc * 8,
                  &Ab[(i * 256 + w * 64) * 8]);
    }
    #pragma unroll
    for (int i = 0; i < 4; ++i) {
      int c = i * 256 + t;
      int row = c >> 3, cc = c & 7, scc = cc ^ (row & 7);
      gload_lds16(Bt + (size_t)(colBase + row) * K + kk + scc * 8,
                  &Bb[(i * 256 + w * 64) * 8]);
    }
    __syncthreads();
    #pragma unroll
    for (int ks = 0; ks < 2; ++ks) {
      short8 af[4], bf[4];
      const int kb = (ks * 32 + g4 * 8) * 2;
      #pragma unroll
      for (int m = 0; m < 4; ++m) {
        int row = wm * 64 + m * 16 + l15;
        af[m] = *(const short8*)((const char*)Ab + row * 128 + (kb ^ ((row & 7) << 4)));
      }
      #pragma unroll
      for (int n = 0; n < 4; ++n) {
        int row = wn * 64 + n * 16 + l15;
        bf[n] = *(const short8*)((const char*)Bb + row * 128 + (kb ^ ((row & 7) << 4)));
      }
      #pragma unroll
      for (int m = 0; m < 4; ++m)
        #pragma unroll
        for (int n = 0; n < 4; ++n)
          acc[m][n] = __builtin_amdgcn_mfma_f32_16x16x32_bf16(af[m], bf[n], acc[m][n], 0, 0, 0);
    }
  }

  float bv[4];
  #pragma unroll
  for (int n = 0; n < 4; ++n) bv[n] = bias[colBase + wn * 64 + n * 16 + l15];
  #pragma unroll
  for (int m = 0; m < 4; ++m)
    #pragma unroll
    for (int r = 0; r < 4; ++r) {
      int grow = rowBase + wm * 64 + m * 16 + g4 * 4 + r;
      if constexpr (EPI == 0) {
        #pragma unroll
        for (int n = 0; n < 4; ++n) {
          int gcol = colBase + wn * 64 + n * 16 + l15;
          ho[(size_t)grow * 1024u + gcol] = f2bf(gelu_fast(acc[m][n][r] + bv[n]));
        }
      } else {
        u32 b_ = (u32)grow / 49u, nn = (u32)grow - b_ * 49u;
        u32 bbi = b_ >> 6, wv = b_ & 63u, wy = wv >> 3, wx = wv & 7u;
        u32 ii = nn / 7u, jj = nn - ii * 7u;
        u32 y = wy * 7u + ii + 3u;  if (y >= 56u) y -= 56u;
        u32 xx = wx * 7u + jj + 3u; if (xx >= 56u) xx -= 56u;
        size_t orow = ((size_t)(bbi * 3136u + y * 56u + xx)) * 256u;
        #pragma unroll
        for (int n = 0; n < 4; ++n) {
          int gcol = colBase + wn * 64 + n * 16 + l15;
          float xv = bf2f(x2g[(size_t)grow * 256u + gcol]);
          out[orow + gcol] = acc[m][n][r] + bv[n] + xv;
        }
      }
    }
}

extern "C" void kernel_launch(void* const* d_in, const int* in_sizes, int n_in,
                              void* d_out, int out_size, void* d_ws, size_t ws_size,
                              hipStream_t stream) {
  (void)in_sizes; (void)n_in; (void)out_size; (void)ws_size;
  const float* x    = (const float*)d_in[0];
  const float* n1g  = (const float*)d_in[1];
  const float* n1b  = (const float*)d_in[2];
  const float* qkvw = (const float*)d_in[3];
  const float* qkvb = (const float*)d_in[4];
  const float* rpb  = (const float*)d_in[5];
  const float* pw   = (const float*)d_in[6];
  const float* pb   = (const float*)d_in[7];
  const float* n2g  = (const float*)d_in[8];
  const float* n2b  = (const float*)d_in[9];
  const float* f1w  = (const float*)d_in[10];
  const float* f1b  = (const float*)d_in[11];
  const float* f2w  = (const float*)d_in[12];
  const float* f2b  = (const float*)d_in[13];
  float* out = (float*)d_out;

  char* ws = (char*)d_ws;
  u16* wA     = (u16*)ws;                        // 102,760,448 (ln1 out)
  u16* qkvbuf = (u16*)(ws + 102760448);          // 308,281,344
  u16* hid    = (u16*)ws;                        // 411,041,792 — overlays wA+qkvbuf (dead after attn)
  u16* x2g    = (u16*)(ws + 411041792);          // 102,760,448 (x2, bf16, window order)
  u16* lno    = (u16*)(ws + 513802240);          // 102,760,448 (ln2 out, bf16, window order)
  float* bmtab = (float*)(ws + 616562688);       // 524,288
  u16* wtq  = (u16*)(ws + 617086976);            // 393,216
  u16* wtp  = (u16*)(ws + 617480192);            // 131,072
  u16* wtf1 = (u16*)(ws + 617611264);            // 524,288
  u16* wtf2 = (u16*)(ws + 618135552);            // 524,288

  wtrans_kernel<<<768, 256, 0, stream>>>(qkvw, wtq, 256, 768);
  wtrans_kernel<<<256, 256, 0, stream>>>(pw, wtp, 256, 256);
  wtrans_kernel<<<1024, 256, 0, stream>>>(f1w, wtf1, 256, 1024);
  wtrans_kernel<<<1024, 256, 0, stream>>>(f2w, wtf2, 1024, 256);
  biasmask_kernel<<<512, 256, 0, stream>>>(rpb, bmtab);

  ln_kernel<<<50176, 256, 0, stream>>>(x, n1g, n1b, wA);
  qkv_gemm<<<9408, 256, 0, stream>>>(wA, wtq, qkvb, qkvbuf);
  attn_mega<<<4096, 512, 0, stream>>>(qkvbuf, bmtab, wtp, pb, x, n2g, n2b, x2g, lno);
  mlp_gemm<0><<<12544, 256, 0, stream>>>(lno, wtf1, 256, 8, f1b, nullptr, hid, nullptr);
  mlp_gemm<1><<<3136, 256, 0, stream>>>(hid, wtf2, 1024, 2, f2b, x2g, nullptr, out);
}

// Round 20
// 875.632 us; speedup vs baseline: 1.0789x; 1.0789x over previous
//
#include <hip/hip_runtime.h>
#include <hip/hip_bf16.h>

typedef unsigned short u16;
typedef unsigned int u32;
typedef __attribute__((ext_vector_type(8))) short short8;
typedef __attribute__((ext_vector_type(4))) float f32x4;
typedef __attribute__((ext_vector_type(2))) unsigned int u32x2;

#define DEVFN static __device__ __forceinline__

DEVFN u16 f2bf(float f) {
  union { float f; u32 i; } v; v.f = f;
  return (u16)((v.i + 0x7fffu + ((v.i >> 16) & 1u)) >> 16);
}
DEVFN float bf2f(u16 u) {
  union { u32 i; float f; } v; v.i = ((u32)u) << 16; return v.f;
}
DEVFN void gload_lds16(const void* g, void* l) {
  __builtin_amdgcn_global_load_lds((const __attribute__((address_space(1))) u32*)g,
                                   (__attribute__((address_space(3))) u32*)l, 16, 0, 0);
}
DEVFN u32 cvt_pk_bf16(float lo, float hi) {
  u32 r;
  asm("v_cvt_pk_bf16_f32 %0, %1, %2" : "=v"(r) : "v"(lo), "v"(hi));
  return r;
}
// tanh-form GELU via sigmoid: gelu(x) ~= x * sigmoid(1.59577x + 0.0713548x^3)
DEVFN float gelu_fast(float v) {
  float s = v * (1.5957691216057308f + 0.07135481627f * v * v);
  return v / (1.0f + __expf(-s));
}

// ---------------- weight transpose: W (K x N, f32) -> Wt (N x K, bf16) ----------
__global__ void wtrans_kernel(const float* __restrict__ w, u16* __restrict__ wt, int K, int N) {
  int idx = blockIdx.x * 256 + threadIdx.x;
  if (idx >= K * N) return;
  int n = idx / K, k = idx - n * K;
  wt[idx] = f2bf(w[(size_t)k * N + n]);
}

// ------- bias+mask table in MFMA C-fragment layout, PRE-SCALED by 1/ln2 --------
__global__ void biasmask_kernel(const float* __restrict__ rpb, float* __restrict__ bm) {
  int idx = blockIdx.x * 256 + threadIdx.x;
  if (idx >= 4 * 8 * 16 * 64 * 4) return;
  int rg = idx & 3;
  int lane = (idx >> 2) & 63;
  int mrb = (idx >> 8) & 15;
  int h = (idx >> 12) & 7;
  int t = idx >> 15;
  int m = mrb >> 2, rb = mrb & 3;
  int g4 = lane >> 4, l15 = lane & 15;
  int nn = m * 16 + g4 * 4 + rg;     // key index
  int r = rb * 16 + l15;             // query index
  float v;
  if (nn >= 49) v = -1e9f;
  else if (r >= 49) v = 0.f;
  else {
    int i1 = r / 7, j1 = r - i1 * 7, i2 = nn / 7, j2 = nn - i2 * 7;
    int rel = (i1 - i2 + 6) * 13 + (j1 - j2 + 6);
    v = rpb[rel * 8 + h];
    int ry1 = (t & 2) ? (i1 < 4 ? 1 : 2) : 0;
    int rx1 = (t & 1) ? (j1 < 4 ? 1 : 2) : 0;
    int ry2 = (t & 2) ? (i2 < 4 ? 1 : 2) : 0;
    int rx2 = (t & 1) ? (j2 < 4 ? 1 : 2) : 0;
    if (ry1 * 3 + rx1 != ry2 * 3 + rx2) v += -100.0f;
  }
  bm[idx] = v * 1.4426950408889634f;   // log2 domain
}

// ---------------- LayerNorm1 (one wave per token) with shift+window gather -----
__global__ void ln_kernel(const float* __restrict__ x, const float* __restrict__ gg,
                          const float* __restrict__ bb, u16* __restrict__ out) {
  int gw = (int)(((u32)blockIdx.x * blockDim.x + threadIdx.x) >> 6);
  int lane = threadIdx.x & 63;
  u32 tw = (u32)gw;
  u32 b_ = tw / 49u, nn = tw - b_ * 49u;
  u32 bbi = b_ >> 6, wv = b_ & 63u, wy = wv >> 3, wx = wv & 7u;
  u32 ii = nn / 7u, jj = nn - ii * 7u;
  u32 y = wy * 7u + ii + 3u;  if (y >= 56u) y -= 56u;
  u32 xx = wx * 7u + jj + 3u; if (xx >= 56u) xx -= 56u;
  size_t src = ((size_t)(bbi * 3136u + y * 56u + xx)) * 256u;
  float4 v = *(const float4*)(x + src + lane * 4);
  float s = v.x + v.y + v.z + v.w;
  float s2 = v.x * v.x + v.y * v.y + v.z * v.z + v.w * v.w;
  #pragma unroll
  for (int m = 1; m < 64; m <<= 1) {
    s += __shfl_xor(s, m, 64);
    s2 += __shfl_xor(s2, m, 64);
  }
  float mu = s * (1.f / 256.f);
  float var = s2 * (1.f / 256.f) - mu * mu;
  float rs = rsqrtf(var + 1e-5f);
  float4 g4 = *(const float4*)(gg + lane * 4);
  float4 b4 = *(const float4*)(bb + lane * 4);
  ushort4 o;
  o.x = f2bf((v.x - mu) * rs * g4.x + b4.x);
  o.y = f2bf((v.y - mu) * rs * g4.y + b4.y);
  o.z = f2bf((v.z - mu) * rs * g4.z + b4.z);
  o.w = f2bf((v.w - mu) * rs * g4.w + b4.w);
  *(ushort4*)(out + (size_t)gw * 256u + lane * 4) = o;
}

// ---------------- QKV GEMM: 128x128 tile, 256 threads (4 waves 2x2) ------------
// Q pre-scaled by d^-0.5 / ln2 (softmax runs in exp2 domain)
__global__ __launch_bounds__(256, 2) void qkv_gemm(
    const u16* __restrict__ A, const u16* __restrict__ Bt,
    const float* __restrict__ bias, u16* __restrict__ C) {
  __shared__ __align__(16) u16 Ab[128 * 64];
  __shared__ __align__(16) u16 Bb[128 * 64];
  const int t = threadIdx.x;
  const int w = t >> 6, lane = t & 63;
  const int wm = w >> 1, wn = w & 1;
  const int g4 = lane >> 4, l15 = lane & 15;
  int bid = blockIdx.x;
  int chunk = (int)gridDim.x >> 3;
  int logical = (bid & 7) * chunk + (bid >> 3);
  const int bx = logical % 6, by = logical / 6;
  const int rowBase = by * 128;
  const int colBase = bx * 128;
  f32x4 acc[4][4] = {};

  for (int kk = 0; kk < 256; kk += 64) {
    __syncthreads();
    #pragma unroll
    for (int i = 0; i < 4; ++i) {
      int c = i * 256 + t;
      int row = c >> 3, cc = c & 7, scc = cc ^ (row & 7);
      gload_lds16(A + (size_t)(rowBase + row) * 256 + kk + scc * 8,
                  &Ab[(i * 256 + w * 64) * 8]);
    }
    #pragma unroll
    for (int i = 0; i < 4; ++i) {
      int c = i * 256 + t;
      int row = c >> 3, cc = c & 7, scc = cc ^ (row & 7);
      gload_lds16(Bt + (size_t)(colBase + row) * 256 + kk + scc * 8,
                  &Bb[(i * 256 + w * 64) * 8]);
    }
    __syncthreads();
    #pragma unroll
    for (int ks = 0; ks < 2; ++ks) {
      short8 af[4], bf[4];
      const int kb = (ks * 32 + g4 * 8) * 2;
      #pragma unroll
      for (int m = 0; m < 4; ++m) {
        int row = wm * 64 + m * 16 + l15;
        af[m] = *(const short8*)((const char*)Ab + row * 128 + (kb ^ ((row & 7) << 4)));
      }
      #pragma unroll
      for (int n = 0; n < 4; ++n) {
        int row = wn * 64 + n * 16 + l15;
        bf[n] = *(const short8*)((const char*)Bb + row * 128 + (kb ^ ((row & 7) << 4)));
      }
      #pragma unroll
      for (int m = 0; m < 4; ++m)
        #pragma unroll
        for (int n = 0; n < 4; ++n)
          acc[m][n] = __builtin_amdgcn_mfma_f32_16x16x32_bf16(af[m], bf[n], acc[m][n], 0, 0, 0);
    }
  }
  // Q scale = 0.17677669529663687 * 1.4426950408889634 (exp2 domain)
  const float scale = (colBase < 256) ? 0.2550348842333775f : 1.0f;
  float bv[4];
  #pragma unroll
  for (int n = 0; n < 4; ++n) bv[n] = bias[colBase + wn * 64 + n * 16 + l15];
  #pragma unroll
  for (int m = 0; m < 4; ++m)
    #pragma unroll
    for (int r = 0; r < 4; ++r) {
      int grow = rowBase + wm * 64 + m * 16 + g4 * 4 + r;
      #pragma unroll
      for (int n = 0; n < 4; ++n) {
        int gcol = colBase + wn * 64 + n * 16 + l15;
        C[(size_t)grow * 768 + gcol] = f2bf((acc[m][n][r] + bv[n]) * scale);
      }
    }
}

// ---------------- mega attention: attn + proj + residual + LN2 per window ------
__global__ __launch_bounds__(512, 4) void attn_mega(
    const u16* __restrict__ qkv, const float* __restrict__ bm2,
    const u16* __restrict__ wtp, const float* __restrict__ pbias,
    const float* __restrict__ x, const float* __restrict__ g2,
    const float* __restrict__ b2, u16* __restrict__ x2g,
    u16* __restrict__ lno) {
  __shared__ __align__(16) char smem[65536];
  __shared__ __align__(16) float redbuf[64][4][2];
  const int t = threadIdx.x;
  const int w = t >> 6, lane = t & 63;
  const int g4 = lane >> 4, l15 = lane & 15;
  const int b_ = blockIdx.x;
  const int wv = b_ & 63, wy = wv >> 3, wx = wv & 7;
  const int mtype = ((wy == 7) ? 2 : 0) + ((wx == 7) ? 1 : 0);
  const int h = w;
  const size_t gbase = (size_t)b_ * 49u * 768u;

  short8 qf[4], kf[4];
  #pragma unroll
  for (int i = 0; i < 4; ++i) {
    int r = i * 16 + l15; if (r > 48) r = 48;
    qf[i] = *(const short8*)(qkv + gbase + (size_t)r * 768 + h * 32 + g4 * 8);
    kf[i] = *(const short8*)(qkv + gbase + (size_t)r * 768 + 256 + h * 32 + g4 * 8);
  }
  f32x4 s[4][4];
  const float* bmp = bm2 + ((size_t)(mtype * 8 + h) * 16) * 256 + lane * 4;
  #pragma unroll
  for (int m = 0; m < 4; ++m)
    #pragma unroll
    for (int rb = 0; rb < 4; ++rb)
      s[m][rb] = *(const f32x4*)(bmp + (m * 4 + rb) * 256);
  #pragma unroll
  for (int m = 0; m < 4; ++m)
    #pragma unroll
    for (int rb = 0; rb < 4; ++rb)
      s[m][rb] = __builtin_amdgcn_mfma_f32_16x16x32_bf16(kf[m], qf[rb], s[m][rb], 0, 0, 0);

  short8 vf[2][2];
  #pragma unroll
  for (int ks = 0; ks < 2; ++ks) {
    #pragma unroll
    for (int nd = 0; nd < 2; ++nd) {
      int dd = nd * 16 + l15;
      #pragma unroll
      for (int j = 0; j < 8; ++j) {
        int n = ks * 32 + g4 * 8 + j;
        vf[ks][nd][j] = (short)qkv[gbase + (size_t)n * 768 + 512 + h * 32 + dd];
      }
    }
  }

  char* pw = smem + w * 8192;
  #pragma unroll
  for (int rb = 0; rb < 4; ++rb) {
    int r = rb * 16 + l15;
    float mx = -1e30f;
    #pragma unroll
    for (int m = 0; m < 4; ++m)
      #pragma unroll
      for (int rg = 0; rg < 4; ++rg)
        mx = fmaxf(mx, s[m][rb][rg]);
    mx = fmaxf(mx, __shfl_xor(mx, 16, 64));
    mx = fmaxf(mx, __shfl_xor(mx, 32, 64));
    float sum = 0.f;
    #pragma unroll
    for (int m = 0; m < 4; ++m)
      #pragma unroll
      for (int rg = 0; rg < 4; ++rg) {
        float e = exp2f(s[m][rb][rg] - mx);
        s[m][rb][rg] = e;
        sum += e;
      }
    sum += __shfl_xor(sum, 16, 64);
    sum += __shfl_xor(sum, 32, 64);
    float inv = 1.0f / sum;
    #pragma unroll
    for (int m = 0; m < 4; ++m) {
      u32x2 pk;
      pk.x = cvt_pk_bf16(s[m][rb][0] * inv, s[m][rb][1] * inv);
      pk.y = cvt_pk_bf16(s[m][rb][2] * inv, s[m][rb][3] * inv);
      int nn0 = m * 16 + g4 * 4;
      *(u32x2*)(pw + r * 128 + ((nn0 * 2) ^ ((r & 7) << 4))) = pk;
    }
  }

  f32x4 o[4][2] = {};
  #pragma unroll
  for (int ks = 0; ks < 2; ++ks) {
    short8 pf[4];
    const int kbyt = (ks * 32 + g4 * 8) * 2;
    #pragma unroll
    for (int ma = 0; ma < 4; ++ma) {
      int r = ma * 16 + l15;
      pf[ma] = *(const short8*)(pw + r * 128 + (kbyt ^ ((r & 7) << 4)));
    }
    #pragma unroll
    for (int ma = 0; ma < 4; ++ma)
      #pragma unroll
      for (int nd = 0; nd < 2; ++nd)
        o[ma][nd] = __builtin_amdgcn_mfma_f32_16x16x32_bf16(pf[ma], vf[ks][nd], o[ma][nd], 0, 0, 0);
  }

  const int wm2 = w >> 2, wn2 = w & 3;
  const u32 bbi = (u32)b_ >> 6;
  float xr[2][4][4];
  #pragma unroll
  for (int mf = 0; mf < 2; ++mf)
    #pragma unroll
    for (int rg = 0; rg < 4; ++rg) {
      int r = wm2 * 32 + mf * 16 + g4 * 4 + rg;
      u32 ii = (u32)r / 7u, jj = (u32)r - ii * 7u;
      u32 y = (u32)wy * 7u + ii + 3u;  if (y >= 56u) y -= 56u;
      u32 xx = (u32)wx * 7u + jj + 3u; if (xx >= 56u) xx -= 56u;
      size_t orowx = ((size_t)(bbi * 3136u + y * 56u + xx)) * 256u;
      #pragma unroll
      for (int nf = 0; nf < 4; ++nf)
        xr[mf][nf][rg] = x[orowx + wn2 * 64 + nf * 16 + l15];
    }

  __syncthreads();

  #pragma unroll
  for (int ma = 0; ma < 4; ++ma)
    #pragma unroll
    for (int nd = 0; nd < 2; ++nd)
      #pragma unroll
      for (int rg = 0; rg < 4; ++rg) {
        int r = ma * 16 + g4 * 4 + rg;
        int colb = (h * 32 + nd * 16 + l15) * 2;
        *(u16*)(smem + r * 512 + (colb ^ ((r & 7) << 4))) = f2bf(o[ma][nd][rg]);
      }
  __syncthreads();

  f32x4 ap[2][4] = {};
  for (int kk = 0; kk < 256; kk += 64) {
    #pragma unroll
    for (int i = 0; i < 4; ++i) {
      int c = i * 512 + w * 64 + lane;
      int n = c >> 3, cc = c & 7, scc = cc ^ (n & 7);
      gload_lds16(wtp + (size_t)n * 256 + kk + scc * 8,
                  smem + 32768 + (size_t)(i * 512 + w * 64) * 16);
    }
    __syncthreads();
    #pragma unroll
    for (int ks2 = 0; ks2 < 2; ++ks2) {
      short8 afr[2], bfr[4];
      int k = kk + ks2 * 32 + g4 * 8;
      #pragma unroll
      for (int mf = 0; mf < 2; ++mf) {
        int r = wm2 * 32 + mf * 16 + l15;
        afr[mf] = *(const short8*)(smem + r * 512 + ((k * 2) ^ ((r & 7) << 4)));
      }
      #pragma unroll
      for (int nf = 0; nf < 4; ++nf) {
        int n = wn2 * 64 + nf * 16 + l15;
        bfr[nf] = *(const short8*)(smem + 32768 + n * 128 + (((ks2 * 4 + g4) ^ (n & 7)) << 4));
      }
      #pragma unroll
      for (int mf = 0; mf < 2; ++mf)
        #pragma unroll
        for (int nf = 0; nf < 4; ++nf)
          ap[mf][nf] = __builtin_amdgcn_mfma_f32_16x16x32_bf16(afr[mf], bfr[nf], ap[mf][nf], 0, 0, 0);
    }
    __syncthreads();
  }

  float pb4[4];
  #pragma unroll
  for (int nf = 0; nf < 4; ++nf) pb4[nf] = pbias[wn2 * 64 + nf * 16 + l15];
  float vv[2][4][4];
  #pragma unroll
  for (int mf = 0; mf < 2; ++mf)
    #pragma unroll
    for (int rg = 0; rg < 4; ++rg) {
      int r = wm2 * 32 + mf * 16 + g4 * 4 + rg;
      float s1 = 0.f, s2 = 0.f;
      #pragma unroll
      for (int nf = 0; nf < 4; ++nf) {
        float v = ap[mf][nf][rg] + pb4[nf] + xr[mf][nf][rg];
        vv[mf][nf][rg] = v;
        s1 += v; s2 += v * v;
      }
      #pragma unroll
      for (int m2 = 1; m2 < 16; m2 <<= 1) {
        s1 += __shfl_xor(s1, m2, 64);
        s2 += __shfl_xor(s2, m2, 64);
      }
      if (l15 == 0) { redbuf[r][wn2][0] = s1; redbuf[r][wn2][1] = s2; }
    }
  __syncthreads();
  #pragma unroll
  for (int mf = 0; mf < 2; ++mf)
    #pragma unroll
    for (int rg = 0; rg < 4; ++rg) {
      int r = wm2 * 32 + mf * 16 + g4 * 4 + rg;
      if (r < 49) {
        float s1 = redbuf[r][0][0] + redbuf[r][1][0] + redbuf[r][2][0] + redbuf[r][3][0];
        float s2 = redbuf[r][0][1] + redbuf[r][1][1] + redbuf[r][2][1] + redbuf[r][3][1];
        float mu = s1 * (1.f / 256.f);
        float var = s2 * (1.f / 256.f) - mu * mu;
        float rs = rsqrtf(var + 1e-5f);
        size_t orow = ((size_t)b_ * 49u + r) * 256u;
        #pragma unroll
        for (int nf = 0; nf < 4; ++nf) {
          int col = wn2 * 64 + nf * 16 + l15;
          float v = vv[mf][nf][rg];
          x2g[orow + col] = f2bf(v);
          lno[orow + col] = f2bf((v - mu) * rs * g2[col] + b2[col]);
        }
      }
    }
}

// ---------------- MLP GEMMs: 128x128 tile, 256 threads (4 waves 2x2) -----------
// EPI 0: fc1 -> bias + fast gelu -> bf16 hid (row stride 1024)
// EPI 1: fc2 -> bias + x2 residual + un-permute -> fp32 out
template<int EPI>
__global__ __launch_bounds__(256, 2) void mlp_gemm(
    const u16* __restrict__ A, const u16* __restrict__ Bt, int K, int nbx,
    const float* __restrict__ bias, const u16* __restrict__ x2g,
    u16* __restrict__ ho, float* __restrict__ out) {
  __shared__ __align__(16) u16 Ab[128 * 64];
  __shared__ __align__(16) u16 Bb[128 * 64];
  const int t = threadIdx.x;
  const int w = t >> 6, lane = t & 63;
  const int wm = w >> 1, wn = w & 1;
  const int g4 = lane >> 4, l15 = lane & 15;
  int bid = blockIdx.x;
  int chunk = (int)gridDim.x >> 3;
  int logical = (bid & 7) * chunk + (bid >> 3);
  const int bx = logical % nbx, by = logical / nbx;
  const int rowBase = by * 128;
  const int colBase = bx * 128;
  f32x4 acc[4][4] = {};

  for (int kk = 0; kk < K; kk += 64) {
    __syncthreads();
    #pragma unroll
    for (int i = 0; i < 4; ++i) {
      int c = i * 256 + t;
      int row = c >> 3, cc = c & 7, scc = cc ^ (row & 7);
      gload_lds16(A + (size_t)(rowBase + row) * K + kk + scc * 8,
                  &Ab[(i * 256 + w * 64) * 8]);
    }
    #pragma unroll
    for (int i = 0; i < 4; ++i) {
      int c = i * 256 + t;
      int row = c >> 3, cc = c & 7, scc = cc ^ (row & 7);
      gload_lds16(Bt + (size_t)(colBase + row) * K + kk + scc * 8,
                  &Bb[(i * 256 + w * 64) * 8]);
    }
    __syncthreads();
    #pragma unroll
    for (int ks = 0; ks < 2; ++ks) {
      short8 af[4], bf[4];
      const int kb = (ks * 32 + g4 * 8) * 2;
      #pragma unroll
      for (int m = 0; m < 4; ++m) {
        int row = wm * 64 + m * 16 + l15;
        af[m] = *(const short8*)((const char*)Ab + row * 128 + (kb ^ ((row & 7) << 4)));
      }
      #pragma unroll
      for (int n = 0; n < 4; ++n) {
        int row = wn * 64 + n * 16 + l15;
        bf[n] = *(const short8*)((const char*)Bb + row * 128 + (kb ^ ((row & 7) << 4)));
      }
      #pragma unroll
      for (int m = 0; m < 4; ++m)
        #pragma unroll
        for (int n = 0; n < 4; ++n)
          acc[m][n] = __builtin_amdgcn_mfma_f32_16x16x32_bf16(af[m], bf[n], acc[m][n], 0, 0, 0);
    }
  }

  float bv[4];
  #pragma unroll
  for (int n = 0; n < 4; ++n) bv[n] = bias[colBase + wn * 64 + n * 16 + l15];
  #pragma unroll
  for (int m = 0; m < 4; ++m)
    #pragma unroll
    for (int r = 0; r < 4; ++r) {
      int grow = rowBase + wm * 64 + m * 16 + g4 * 4 + r;
      if constexpr (EPI == 0) {
        #pragma unroll
        for (int n = 0; n < 4; ++n) {
          int gcol = colBase + wn * 64 + n * 16 + l15;
          ho[(size_t)grow * 1024u + gcol] = f2bf(gelu_fast(acc[m][n][r] + bv[n]));
        }
      } else {
        u32 b_ = (u32)grow / 49u, nn = (u32)grow - b_ * 49u;
        u32 bbi = b_ >> 6, wv = b_ & 63u, wy = wv >> 3, wx = wv & 7u;
        u32 ii = nn / 7u, jj = nn - ii * 7u;
        u32 y = wy * 7u + ii + 3u;  if (y >= 56u) y -= 56u;
        u32 xx = wx * 7u + jj + 3u; if (xx >= 56u) xx -= 56u;
        size_t orow = ((size_t)(bbi * 3136u + y * 56u + xx)) * 256u;
        #pragma unroll
        for (int n = 0; n < 4; ++n) {
          int gcol = colBase + wn * 64 + n * 16 + l15;
          float xv = bf2f(x2g[(size_t)grow * 256u + gcol]);
          out[orow + gcol] = acc[m][n][r] + bv[n] + xv;
        }
      }
    }
}

extern "C" void kernel_launch(void* const* d_in, const int* in_sizes, int n_in,
                              void* d_out, int out_size, void* d_ws, size_t ws_size,
                              hipStream_t stream) {
  (void)in_sizes; (void)n_in; (void)out_size; (void)ws_size;
  const float* x    = (const float*)d_in[0];
  const float* n1g  = (const float*)d_in[1];
  const float* n1b  = (const float*)d_in[2];
  const float* qkvw = (const float*)d_in[3];
  const float* qkvb = (const float*)d_in[4];
  const float* rpb  = (const float*)d_in[5];
  const float* pw   = (const float*)d_in[6];
  const float* pb   = (const float*)d_in[7];
  const float* n2g  = (const float*)d_in[8];
  const float* n2b  = (const float*)d_in[9];
  const float* f1w  = (const float*)d_in[10];
  const float* f1b  = (const float*)d_in[11];
  const float* f2w  = (const float*)d_in[12];
  const float* f2b  = (const float*)d_in[13];
  float* out = (float*)d_out;

  char* ws = (char*)d_ws;
  u16* wA     = (u16*)ws;                        // 102,760,448 (ln1 out)
  u16* qkvbuf = (u16*)(ws + 102760448);          // 308,281,344
  u16* hid    = (u16*)ws;                        // 411,041,792 — overlays wA+qkvbuf (dead after attn)
  u16* x2g    = (u16*)(ws + 411041792);          // 102,760,448 (x2, bf16, window order)
  u16* lno    = (u16*)(ws + 513802240);          // 102,760,448 (ln2 out, bf16, window order)
  float* bmtab = (float*)(ws + 616562688);       // 524,288
  u16* wtq  = (u16*)(ws + 617086976);            // 393,216
  u16* wtp  = (u16*)(ws + 617480192);            // 131,072
  u16* wtf1 = (u16*)(ws + 617611264);            // 524,288
  u16* wtf2 = (u16*)(ws + 618135552);            // 524,288

  wtrans_kernel<<<768, 256, 0, stream>>>(qkvw, wtq, 256, 768);
  wtrans_kernel<<<256, 256, 0, stream>>>(pw, wtp, 256, 256);
  wtrans_kernel<<<1024, 256, 0, stream>>>(f1w, wtf1, 256, 1024);
  wtrans_kernel<<<1024, 256, 0, stream>>>(f2w, wtf2, 1024, 256);
  biasmask_kernel<<<512, 256, 0, stream>>>(rpb, bmtab);

  ln_kernel<<<50176, 256, 0, stream>>>(x, n1g, n1b, wA);
  qkv_gemm<<<9408, 256, 0, stream>>>(wA, wtq, qkvb, qkvbuf);
  attn_mega<<<4096, 512, 0, stream>>>(qkvbuf, bmtab, wtp, pb, x, n2g, n2b, x2g, lno);
  mlp_gemm<0><<<12544, 256, 0, stream>>>(lno, wtf1, 256, 8, f1b, nullptr, hid, nullptr);
  mlp_gemm<1><<<3136, 256, 0, stream>>>(hid, wtf2, 1024, 2, f2b, x2g, nullptr, out);
}